// Round 1
// 482.354 us; speedup vs baseline: 1.0076x; 1.0076x over previous
//
#include <hip/hip_runtime.h>
#include <cmath>

#define BATCH     16384
#define CTX       10
#define NSENSE    8
#define VEC_DIM   128
#define XCOLS     (2 + CTX)

typedef float f4 __attribute__((ext_vector_type(4)));

// 32 lanes per batch element, 4 dims/lane (one float4 = 16 B per lane).
// Every row gather is now ONE wave-instruction spanning exactly one
// contiguous 512-B row: 8 dense 64-B lines, no half-consumed split reads
// (the old 16-lane/8-dim layout touched 32 lines per instr at 16 B each).
// 2x the waves (8192 -> 8/SIMD capacity) for latency hiding.
// W_s rows have no cross-element reuse -> nontemporal, so they don't evict
// the ~51 MB W_g table (1.8x reuse within a run) from L2/L3.
__global__ __launch_bounds__(256) void SenseEmbedding_40295383171457_kernel(
    const int*   __restrict__ x,     // [BATCH, 12]
    const float* __restrict__ Wg,    // [VOCAB, 128]
    const float* __restrict__ Ws,    // [VOCAB, 8, 128]
    float*       __restrict__ out)   // [BATCH, 1]
{
    const int gtid = blockIdx.x * blockDim.x + threadIdx.x;
    const int elem = gtid >> 5;          // 32 lanes per element
    const int sub  = gtid & 31;
    if (elem >= BATCH) return;

    // x row is 48 B, 16 B-aligned -> 3 int4 loads (same addr across the
    // 32-lane group -> single line request, broadcast).
    const int4* xr4 = reinterpret_cast<const int4*>(x + elem * XCOLS);
    const int4 xa = xr4[0];   // w0, w1, ctx0, ctx1
    const int4 xb = xr4[1];   // ctx2..ctx5
    const int4 xc = xr4[2];   // ctx6..ctx9
    const int off = sub * 4;  // this lane's contiguous 4-float slice

    // Target row (independent of everything else; issues early).
    const f4 t = *reinterpret_cast<const f4*>(
        Wg + (unsigned)xa.y * VEC_DIM + off);

    // ---- sum_context over 10 gathered W_g rows ----
    const int cidx[CTX] = {xa.z, xa.w, xb.x, xb.y, xb.z, xb.w,
                           xc.x, xc.y, xc.z, xc.w};
    f4 c = {0.f, 0.f, 0.f, 0.f};
    #pragma unroll
    for (int i = 0; i < CTX; ++i) {
        const f4 a = *reinterpret_cast<const f4*>(
            Wg + (unsigned)cidx[i] * VEC_DIM + off);
        c += a;
    }

    // ---- per-sense: score partial p_k AND target-dot partial q_k ----
    // W_s[x0] is 4 KB contiguous; nontemporal: zero reuse stream.
    const float* srow = Ws + (unsigned)xa.x * (NSENSE * VEC_DIM) + off;
    float p[NSENSE], q[NSENSE];
    #pragma unroll
    for (int k = 0; k < NSENSE; ++k) {
        const f4 a = __builtin_nontemporal_load(
            reinterpret_cast<const f4*>(srow + k * VEC_DIM));
        p[k] = a.x * c.x + a.y * c.y + a.z * c.z + a.w * c.w;
        q[k] = a.x * t.x + a.y * t.y + a.z * t.z + a.w * t.w;
    }

    // ---- reduce scores within the 32-lane group ----
    #pragma unroll
    for (int k = 0; k < NSENSE; ++k) {
        float v = p[k];
        #pragma unroll
        for (int s = 16; s > 0; s >>= 1)
            v += __shfl_xor(v, s, 32);
        p[k] = v;   // identical value in all 32 lanes
    }

    // ---- argmax (first-occurrence, group-uniform) ----
    int   best = 0;
    float bv   = p[0];
    #pragma unroll
    for (int k = 1; k < NSENSE; ++k) {
        if (p[k] > bv) { bv = p[k]; best = k; }
    }

    // ---- select q_best (uniform index -> cndmask chain), reduce, sigmoid ----
    float qb = q[0];
    #pragma unroll
    for (int k = 1; k < NSENSE; ++k)
        qb = (best == k) ? q[k] : qb;
    #pragma unroll
    for (int s = 16; s > 0; s >>= 1)
        qb += __shfl_xor(qb, s, 32);

    if (sub == 0) {
        out[elem] = 1.f / (1.f + expf(-qb));
    }
}

extern "C" void kernel_launch(void* const* d_in, const int* in_sizes, int n_in,
                              void* d_out, int out_size, void* d_ws, size_t ws_size,
                              hipStream_t stream) {
    const int*   x  = (const int*)  d_in[0];
    const float* Wg = (const float*)d_in[1];
    const float* Ws = (const float*)d_in[2];
    float*       out = (float*)d_out;

    const int elems_per_block = 256 / 32;               // 8
    const int grid = (BATCH + elems_per_block - 1) / elems_per_block;  // 2048
    SenseEmbedding_40295383171457_kernel<<<grid, 256, 0, stream>>>(x, Wg, Ws, out);
}